// Round 6
// baseline (186.277 us; speedup 1.0000x reference)
//
#include <hip/hip_runtime.h>

typedef __bf16 bf16x8 __attribute__((ext_vector_type(8)));
typedef float f32x4 __attribute__((ext_vector_type(4)));

// Problem constants
#define BB 4
#define CC 64
#define OO 64
#define HH 128
#define WW 128

#define SENT 0x5EC7B412u

// ---------------------------------------------------------------------------
// Single fused kernel, 512 blocks x 256 threads, one graph node.
//   Phase 1: blocks 0..17 prepack weights -> aw (global); ALL blocks prescale
//            their (b,y) row -> xs (global, bf16 channel-innermost).
//   Device-wide barrier: sentinel flags in d_ws (0xAA poison != SENT, so no
//            init needed), agent-scope atomics + __threadfence() (device-scope
//            fence) for cross-XCD visibility. Bounded spin: worst case ->
//            wrong answer (bench fail), never a hang.
//   Phase 2: conv, identical to round-3 kernel (best known: 93.3 us).
// Residency: LDS 56,160 B + __launch_bounds__(256,2) => exactly 2 blocks/CU
// capacity x 256 CU = 512 = grid, so all blocks co-resident.
// LDS union: prescale trans[64][65] f32 (16,640 B) overlaps conv tile.
// ---------------------------------------------------------------------------
__global__ __launch_bounds__(256, 2) void fused_all_kernel(
    const float* __restrict__ in, const float* __restrict__ alpha,
    const float* __restrict__ w, const float* __restrict__ bias,
    const float* __restrict__ pa, const float* __restrict__ pb, const float* __restrict__ pc,
    unsigned short* __restrict__ xs, unsigned short* __restrict__ aw,
    unsigned int* __restrict__ flags, float* __restrict__ out)
{
    __shared__ union {
        float trans[64][65];                  // 16,640 B (phase 1)
        unsigned short tile[3 * 130 * 72];    // 56,160 B (phase 2)
    } sm;

    int bid = blockIdx.x;   // 0..511
    int tid = threadIdx.x;

    // ---------------- Phase 1a: weight prepack (blocks 0..17) ----------------
    if (bid < 18) {
        int gid = bid * 256 + tid;            // 0..4607
        if (gid < 4608) {
            int og  = gid / 1152;
            int rem = gid - og * 1152;
            int t = rem >> 6;
            int l = rem & 63;
            int q = l >> 4;
            int m = l & 15;
            int o  = og * 16 + m;
            int ij = t >> 1;
            int ch = t & 1;
            int i = ij / 3;
            int j = ij - i * 3;
            union { unsigned short u[8]; uint4 v; } pk;
#pragma unroll
            for (int jj = 0; jj < 8; ++jj) {
                int c = ch * 32 + q * 8 + jj;
                float wf = w[((o * CC + c) * 3 + i) * 3 + j];
                __bf16 h = (__bf16)wf;
                pk.u[jj] = __builtin_bit_cast(unsigned short, h);
            }
            ((uint4*)aw)[gid] = pk.v;
        }
    }

    // ---------------- Phase 1b: prescale row (all blocks) --------------------
    // xs[b][y][x][c] = bf16( in[b][c][y][x] * f(alpha[b][y][x]) )
    {
        int y = bid & 127;
        int b = bid >> 7;
        float A  = *pa, Bc = *pb, Cc = *pc;
        int x  = tid & 63;
        int c4 = tid >> 6;                // 0..3
        int xw = tid >> 2;
        int cg = tid & 3;
#pragma unroll
        for (int xh = 0; xh < 2; ++xh) {
            int x0 = xh * 64;
            float av = alpha[(b * HH + y) * WW + x0 + x];
            float f  = (A * av + Bc) * av + Cc;
#pragma unroll
            for (int k = 0; k < 16; ++k) {
                int c = c4 * 16 + k;
                float v = in[((b * CC + c) * HH + y) * WW + x0 + x];
                sm.trans[c][x] = v * f;
            }
            __syncthreads();
            union { unsigned short u[16]; uint4 v4[2]; } pk;
#pragma unroll
            for (int k = 0; k < 16; ++k) {
                __bf16 h = (__bf16)sm.trans[cg * 16 + k][xw];
                pk.u[k] = __builtin_bit_cast(unsigned short, h);
            }
            uint4* dst = (uint4*)(xs + (((size_t)(b * HH + y) * WW + x0 + xw) * CC + cg * 16));
            dst[0] = pk.v4[0];
            dst[1] = pk.v4[1];
            __syncthreads();
        }
    }

    // ---------------- Device-wide barrier ------------------------------------
    __syncthreads();          // all block's global writes issued
    __threadfence();          // device-scope release: xs/aw visible to all XCDs
    if (tid == 0)
        __hip_atomic_store(&flags[bid], SENT, __ATOMIC_RELAXED, __HIP_MEMORY_SCOPE_AGENT);
    if (tid < 64) {
        bool ok = false;
        for (int it = 0; it < 200000 && !ok; ++it) {
            bool mine = true;
#pragma unroll
            for (int k = 0; k < 8; ++k)
                mine &= (__hip_atomic_load(&flags[k * 64 + tid], __ATOMIC_RELAXED,
                                           __HIP_MEMORY_SCOPE_AGENT) == SENT);
            ok = (__ballot(mine) == ~0ull);
            if (!ok) __builtin_amdgcn_s_sleep(2);
        }
    }
    __threadfence();          // device-scope acquire side
    __syncthreads();

    // ---------------- Phase 2: conv (round-3 kernel, verbatim) ---------------
    // XCD swizzle: xcd = bid&7 -> one (b, y-half) slab per XCD
    int n   = bid;
    int xcd = n & 7;
    int idx = n >> 3;                 // 0..63
    int b   = xcd >> 1;
    int y   = (xcd & 1) * 64 + idx;

    // stage: 3120 16B chunks (r, xt, g); stride 72 shorts = 36 dwords ->
    // b128 accesses minimum-aliasing across banks.
    for (int s = tid; s < 3120; s += 256) {
        int g  = s & 7;
        int rx = s >> 3;            // 0..389
        int r  = rx / 130;
        int xt = rx - r * 130;
        int yy = y + r - 1;
        int xg = xt - 1;
        uint4 val = make_uint4(0u, 0u, 0u, 0u);
        if ((unsigned)yy < (unsigned)HH && (unsigned)xg < (unsigned)WW)
            val = *(const uint4*)(xs + (((size_t)(b * HH + yy) * WW + xg) * CC + g * 8));
        *(uint4*)(sm.tile + (r * 130 + xt) * 72 + g * 8) = val;
    }
    __syncthreads();

    int wv = tid >> 6;
    int l  = tid & 63;
    int oh = wv & 1;    // o-half: o in [oh*32, oh*32+32)
    int nh = wv >> 1;   // x-half: x in [nh*64, nh*64+64)
    int q  = l >> 4;
    int m  = l & 15;

    f32x4 acc[2][4];
#pragma unroll
    for (int ag = 0; ag < 2; ++ag)
#pragma unroll
        for (int nf = 0; nf < 4; ++nf)
            acc[ag][nf] = (f32x4){0.f, 0.f, 0.f, 0.f};

    const uint4* awv = (const uint4*)aw + (size_t)(oh * 2) * 18 * 64 + l;

#pragma unroll 3
    for (int ij = 0; ij < 9; ++ij) {
        const int i = ij / 3;
        const int j = ij - i * 3;
#pragma unroll
        for (int ch = 0; ch < 2; ++ch) {
            const int t = ij * 2 + ch;
            bf16x8 afrag[2], bfrag[4];
#pragma unroll
            for (int ag = 0; ag < 2; ++ag)
                afrag[ag] = __builtin_bit_cast(bf16x8, awv[(ag * 18 + t) * 64]);
#pragma unroll
            for (int nf = 0; nf < 4; ++nf) {
                int xt = nh * 64 + nf * 16 + m + j;   // input x = xt-1 = xout + j - 1
                bfrag[nf] = __builtin_bit_cast(bf16x8,
                    *(const uint4*)(sm.tile + (i * 130 + xt) * 72 + ch * 32 + q * 8));
            }
#pragma unroll
            for (int ag = 0; ag < 2; ++ag)
#pragma unroll
                for (int nf = 0; nf < 4; ++nf)
                    acc[ag][nf] = __builtin_amdgcn_mfma_f32_16x16x32_bf16(
                        afrag[ag], bfrag[nf], acc[ag][nf], 0, 0, 0);
        }
    }

    // epilogue: D layout (m89): o = q*4 + r, x = lane&15
#pragma unroll
    for (int ag = 0; ag < 2; ++ag) {
#pragma unroll
        for (int r = 0; r < 4; ++r) {
            int o = (oh * 2 + ag) * 16 + q * 4 + r;
            float bv = bias[o];
#pragma unroll
            for (int nf = 0; nf < 4; ++nf) {
                int x = nh * 64 + nf * 16 + m;
                out[((size_t)(b * OO + o) * HH + y) * WW + x] = acc[ag][nf][r] + bv;
            }
        }
    }
}

// ---------------------------------------------------------------------------
extern "C" void kernel_launch(void* const* d_in, const int* in_sizes, int n_in,
                              void* d_out, int out_size, void* d_ws, size_t ws_size,
                              hipStream_t stream) {
    const float* inputs = (const float*)d_in[0];
    const float* alpha  = (const float*)d_in[1];
    const float* weight = (const float*)d_in[2];
    const float* bias   = (const float*)d_in[3];
    const float* pa     = (const float*)d_in[4];
    const float* pb     = (const float*)d_in[5];
    const float* pc     = (const float*)d_in[6];
    float* out = (float*)d_out;

    unsigned short* aw    = (unsigned short*)d_ws;                      // 73,728 B
    unsigned short* xs    = (unsigned short*)((char*)d_ws + 131072);    // 8,388,608 B
    unsigned int*   flags = (unsigned int*)((char*)d_ws + (16u << 20)); // 2,048 B

    fused_all_kernel<<<512, 256, 0, stream>>>(inputs, alpha, weight, bias,
                                              pa, pb, pc, xs, aw, flags, out);
}

// Round 7
// 95.099 us; speedup vs baseline: 1.9588x; 1.9588x over previous
//
#include <hip/hip_runtime.h>

typedef __bf16 bf16x8 __attribute__((ext_vector_type(8)));
typedef float f32x4 __attribute__((ext_vector_type(4)));

// Problem constants
#define BB 4
#define CC 64
#define OO 64
#define HH 128
#define WW 128

// ---------------------------------------------------------------------------
// Kernel 1 "prep": blocks 0..511 = prescale+transpose (one (b,y) row each),
// blocks 512..529 = weight prepack.
//
// prescale phase A: float4 copy of in[b][:][y][:] (64c x 128x fp32) into
//   trans[64][132] (stride 132 dwords: b128 residues (c+x16)%8 uniform ->
//   balanced; scalar-read banks (4k+xw)%32 2-way -> free).
// prescale phase B: thread owns x=tid>>1, c-half=tid&1. f(alpha[x]) computed
//   once, 32 scaled bf16 packs, one contiguous 64B store to xs[b][y][x][c].
// prepack: aw16[(((og*18)+t)*64+l)*8+jj] = bf16 W[o][c][i][j] in MFMA A-frag
//   order; t=(i*3+j)*2+ch, c=ch*32+(l>>4)*8+jj, o=og*16+(l&15).
// ---------------------------------------------------------------------------
__global__ __launch_bounds__(256) void prep_kernel(
    const float* __restrict__ in, const float* __restrict__ alpha,
    const float* __restrict__ w,
    const float* __restrict__ pa, const float* __restrict__ pb, const float* __restrict__ pc,
    unsigned short* __restrict__ xs, unsigned short* __restrict__ aw)
{
    __shared__ float trans[64][132];   // 33,792 B
    int tid = threadIdx.x;

    if (blockIdx.x >= 512) {
        // ---- prepack branch ----
        int gid = (blockIdx.x - 512) * 256 + tid;   // 0..4607
        if (gid >= 4608) return;
        int og  = gid / 1152;
        int rem = gid - og * 1152;
        int t = rem >> 6;
        int l = rem & 63;
        int q = l >> 4;
        int m = l & 15;
        int o  = og * 16 + m;
        int ij = t >> 1;
        int ch = t & 1;
        int i = ij / 3;
        int j = ij - i * 3;
        union { unsigned short u[8]; uint4 v; } pk;
#pragma unroll
        for (int jj = 0; jj < 8; ++jj) {
            int c = ch * 32 + q * 8 + jj;
            float wf = w[((o * CC + c) * 3 + i) * 3 + j];
            __bf16 h = (__bf16)wf;
            pk.u[jj] = __builtin_bit_cast(unsigned short, h);
        }
        ((uint4*)aw)[gid] = pk.v;
        return;
    }

    // ---- prescale branch ----
    int bid = blockIdx.x;             // 0..511
    int y   = bid & 127;
    int b   = bid >> 7;

    // phase A: float4 copy 64c x 128x into trans
    int x16 = tid & 31;               // float4 index; x = x16*4
    int c8  = tid >> 5;               // 0..7
    const float* src = in + ((size_t)(b * CC) * HH + y) * WW;
#pragma unroll
    for (int k = 0; k < 8; ++k) {
        int c = c8 * 8 + k;
        float4 v = *(const float4*)(src + (size_t)c * HH * WW + x16 * 4);
        *(float4*)(&trans[c][x16 * 4]) = v;
    }
    __syncthreads();

    // phase B: scale + bf16 pack + contiguous 64B store
    int xw = tid >> 1;                // 0..127
    int cg = tid & 1;                 // c-half
    float A  = *pa, Bc = *pb, Cc = *pc;
    float av = alpha[(b * HH + y) * WW + xw];
    float f  = (A * av + Bc) * av + Cc;
    union { unsigned short u[32]; uint4 v4[4]; } pk;
#pragma unroll
    for (int k = 0; k < 32; ++k) {
        __bf16 h = (__bf16)(trans[cg * 32 + k][xw] * f);
        pk.u[k] = __builtin_bit_cast(unsigned short, h);
    }
    uint4* dst = (uint4*)(xs + (((size_t)(b * HH + y) * WW + xw) * CC + cg * 32));
    dst[0] = pk.v4[0];
    dst[1] = pk.v4[1];
    dst[2] = pk.v4[2];
    dst[3] = pk.v4[3];
}

// ---------------------------------------------------------------------------
// Kernel 2: conv (round-3 verbatim — best known config, 93.3 us total).
// One block per (b, y): 64 o x 128 x outputs. 4 waves; 2x4
// mfma_f32_16x16x32_bf16 acc per wave. LDS tile[3][130][72] shorts: stride
// 36 dwords -> staging writes and bfrag b128 reads minimum-aliasing.
// ---------------------------------------------------------------------------
__global__ __launch_bounds__(256, 2) void conv_kernel(
    const unsigned short* __restrict__ xs, const unsigned short* __restrict__ aw,
    const float* __restrict__ bias, float* __restrict__ out)
{
    __shared__ unsigned short tile[3 * 130 * 72];   // 56,160 B

    // XCD swizzle: xcd = bid&7 handles one (b, y-half) slab
    int n   = blockIdx.x;             // 0..511
    int xcd = n & 7;
    int idx = n >> 3;                 // 0..63
    int b   = xcd >> 1;
    int y   = (xcd & 1) * 64 + idx;
    int tid = threadIdx.x;

    // stage: 3120 16B chunks (r, xt, g)
    for (int s = tid; s < 3120; s += 256) {
        int g  = s & 7;
        int rx = s >> 3;            // 0..389
        int r  = rx / 130;
        int xt = rx - r * 130;
        int yy = y + r - 1;
        int xg = xt - 1;
        uint4 val = make_uint4(0u, 0u, 0u, 0u);
        if ((unsigned)yy < (unsigned)HH && (unsigned)xg < (unsigned)WW)
            val = *(const uint4*)(xs + (((size_t)(b * HH + yy) * WW + xg) * CC + g * 8));
        *(uint4*)(tile + (r * 130 + xt) * 72 + g * 8) = val;
    }
    __syncthreads();

    int wv = tid >> 6;
    int l  = tid & 63;
    int oh = wv & 1;    // o-half: o in [oh*32, oh*32+32)
    int nh = wv >> 1;   // x-half: x in [nh*64, nh*64+64)
    int q  = l >> 4;
    int m  = l & 15;

    f32x4 acc[2][4];
#pragma unroll
    for (int ag = 0; ag < 2; ++ag)
#pragma unroll
        for (int nf = 0; nf < 4; ++nf)
            acc[ag][nf] = (f32x4){0.f, 0.f, 0.f, 0.f};

    const uint4* awv = (const uint4*)aw + (size_t)(oh * 2) * 18 * 64 + l;

#pragma unroll 3
    for (int ij = 0; ij < 9; ++ij) {
        const int i = ij / 3;
        const int j = ij - i * 3;
#pragma unroll
        for (int ch = 0; ch < 2; ++ch) {
            const int t = ij * 2 + ch;
            bf16x8 afrag[2], bfrag[4];
#pragma unroll
            for (int ag = 0; ag < 2; ++ag)
                afrag[ag] = __builtin_bit_cast(bf16x8, awv[(ag * 18 + t) * 64]);
#pragma unroll
            for (int nf = 0; nf < 4; ++nf) {
                int xt = nh * 64 + nf * 16 + m + j;   // input x = xt-1 = xout + j - 1
                bfrag[nf] = __builtin_bit_cast(bf16x8,
                    *(const uint4*)(tile + (i * 130 + xt) * 72 + ch * 32 + q * 8));
            }
#pragma unroll
            for (int ag = 0; ag < 2; ++ag)
#pragma unroll
                for (int nf = 0; nf < 4; ++nf)
                    acc[ag][nf] = __builtin_amdgcn_mfma_f32_16x16x32_bf16(
                        afrag[ag], bfrag[nf], acc[ag][nf], 0, 0, 0);
        }
    }

    // epilogue: D layout (m89): o = q*4 + r, x = lane&15
#pragma unroll
    for (int ag = 0; ag < 2; ++ag) {
#pragma unroll
        for (int r = 0; r < 4; ++r) {
            int o = (oh * 2 + ag) * 16 + q * 4 + r;
            float bv = bias[o];
#pragma unroll
            for (int nf = 0; nf < 4; ++nf) {
                int x = nh * 64 + nf * 16 + m;
                out[((size_t)(b * OO + o) * HH + y) * WW + x] = acc[ag][nf][r] + bv;
            }
        }
    }
}

// ---------------------------------------------------------------------------
extern "C" void kernel_launch(void* const* d_in, const int* in_sizes, int n_in,
                              void* d_out, int out_size, void* d_ws, size_t ws_size,
                              hipStream_t stream) {
    const float* inputs = (const float*)d_in[0];
    const float* alpha  = (const float*)d_in[1];
    const float* weight = (const float*)d_in[2];
    const float* bias   = (const float*)d_in[3];
    const float* pa     = (const float*)d_in[4];
    const float* pb     = (const float*)d_in[5];
    const float* pc     = (const float*)d_in[6];
    float* out = (float*)d_out;

    unsigned short* aw = (unsigned short*)d_ws;                       // 73,728 B
    unsigned short* xs = (unsigned short*)((char*)d_ws + 131072);     // 8,388,608 B

    prep_kernel<<<512 + 18, 256, 0, stream>>>(inputs, alpha, weight, pa, pb, pc, xs, aw);
    conv_kernel<<<BB * HH, 256, 0, stream>>>(xs, aw, bias, out);
}